// Round 1
// baseline (246.912 us; speedup 1.0000x reference)
//
#include <hip/hip_runtime.h>

// CNOT (dim=2, wires=12, control=0, target=1) applied to x: (4096, 8192) f32.
//
// U @ x where U is a permutation matrix is a row shuffle:
//   basis index j has control digit = bit 11, target digit = bit 10.
//   p[j] = j with bit10 ^= bit11  (involution: p == p^-1)
//   out[i, :] = x[p[i], :]
//
// Pure memory-bound row-permuted copy: 128 MiB read + 128 MiB write.
// Rows are 32 KiB contiguous -> float4 accesses are fully coalesced.

#define NROWS 4096
#define BATCH 8192
#define ROW_F4 (BATCH / 4)          // 2048 float4 per row
#define TOTAL_F4 (NROWS * ROW_F4)   // 8,388,608

__global__ __launch_bounds__(256) void cnot_perm_kernel(
    const float4* __restrict__ x, float4* __restrict__ out) {
    int t = blockIdx.x * blockDim.x + threadIdx.x;   // < 2^23, fits int
    int row = t >> 11;          // t / ROW_F4
    int col = t & (ROW_F4 - 1); // t % ROW_F4
    // src row: flip bit 10 iff bit 11 set
    int src = row ^ (((row >> 11) & 1) << 10);
    out[(row << 11) | col] = x[(src << 11) | col];
}

extern "C" void kernel_launch(void* const* d_in, const int* in_sizes, int n_in,
                              void* d_out, int out_size, void* d_ws, size_t ws_size,
                              hipStream_t stream) {
    // d_in[0] = U (4096x4096 f32, unused), d_in[1] = x (4096x8192 f32)
    const float4* x = (const float4*)d_in[1];
    float4* out = (float4*)d_out;
    const int block = 256;
    const int grid = TOTAL_F4 / block;  // 32768 blocks, exact cover
    cnot_perm_kernel<<<grid, block, 0, stream>>>(x, out);
}

// Round 3
// 242.160 us; speedup vs baseline: 1.0196x; 1.0196x over previous
//
#include <hip/hip_runtime.h>

// CNOT (dim=2, wires=12, control=0, target=1) on x: (4096, 8192) f32.
//
// U @ x for this U is a row permutation: out[i, :] = x[i ^ (((i>>11)&1)<<10), :]
// (flip bit 10 of the row index iff bit 11 is set; involution).
// Pure streaming copy: 128 MiB read + 128 MiB write, zero FLOPs.
//
// R3: same structure as R2, but use a clang ext_vector float4 — HIP's
// float4 is a struct and __builtin_nontemporal_* rejects it.
// Each block owns 1024 consecutive float4 (16 KiB) of one output row;
// each thread moves 4 float4 strided by 256 lanes: every load/store is one
// contiguous 1 KiB wave transaction, 4 loads in flight before first store.
// Nontemporal both directions — streaming, no reuse, skip L2 allocation.

typedef float v4f __attribute__((ext_vector_type(4)));

#define NROWS 4096
#define ROW_F4 2048            // 8192 floats / 4 per row
#define BLK_F4 1024            // float4 per block
#define BLOCKS (NROWS * ROW_F4 / BLK_F4)   // 8192

__global__ __launch_bounds__(256) void cnot_perm_kernel(
    const v4f* __restrict__ x, v4f* __restrict__ out) {
    const int row  = blockIdx.x >> 1;            // 2 blocks per row
    const int half = (blockIdx.x & 1) << 10;     // 0 or 1024
    const int src  = row ^ (((row >> 11) & 1) << 10);

    const v4f* sp = x   + ((size_t)src << 11) + half + threadIdx.x;
    v4f*       dp = out + ((size_t)row << 11) + half + threadIdx.x;

    v4f a0 = __builtin_nontemporal_load(sp + 0);
    v4f a1 = __builtin_nontemporal_load(sp + 256);
    v4f a2 = __builtin_nontemporal_load(sp + 512);
    v4f a3 = __builtin_nontemporal_load(sp + 768);
    __builtin_nontemporal_store(a0, dp + 0);
    __builtin_nontemporal_store(a1, dp + 256);
    __builtin_nontemporal_store(a2, dp + 512);
    __builtin_nontemporal_store(a3, dp + 768);
}

extern "C" void kernel_launch(void* const* d_in, const int* in_sizes, int n_in,
                              void* d_out, int out_size, void* d_ws, size_t ws_size,
                              hipStream_t stream) {
    // d_in[0] = U (4096x4096 f32, never read), d_in[1] = x (4096x8192 f32)
    const v4f* x = (const v4f*)d_in[1];
    v4f* out = (v4f*)d_out;
    cnot_perm_kernel<<<BLOCKS, 256, 0, stream>>>(x, out);
}